// Round 3
// baseline (1292.718 us; speedup 1.0000x reference)
//
#include <hip/hip_runtime.h>
#include <hip/hip_cooperative_groups.h>
#include <stdint.h>

namespace cg = cooperative_groups;

#define NPIX 65536      // 256*256
#define NRE  65280      // right edges: 256 rows * 255
#define NE   130560     // total edges
#define NIMG 4
#define TPB  1024
#define BPI  64                 // blocks per image
#define NBLK (NIMG*BPI)         // 256 blocks (1 per CU)
#define NT   (BPI*TPB)          // 65536 threads per image
#define MAXR 8192
#define THRESH 8192
#define MASK48 0xFFFFFFFFFFFFULL

__device__ __forceinline__ void edge_uv(int e, int& u, int& v){
  if (e < NRE){ int r = e / 255; int c = e - r*255; u = (r<<8) + c; v = u + 1; }
  else        { u = e - NRE; v = u + 256; }
}

// roots are stable within a phase; concurrent compression writes are benign
__device__ __forceinline__ int find_root(unsigned int* lbl, int x){
  int r = x, c = (int)lbl[r];
  while (c != r){ r = c; c = (int)lbl[r]; }
  while ((int)lbl[x] != r){ int nxt = (int)lbl[x]; lbl[x] = (unsigned)r; x = nxt; }
  return r;
}

__global__ __launch_bounds__(TPB)
void ph0_coop(const float* __restrict__ prob, const float* __restrict__ roi,
              float* __restrict__ Fg, float* __restrict__ LIFEg,
              unsigned int* __restrict__ LBLg, unsigned long long* __restrict__ MEg,
              unsigned long long* __restrict__ LAg, unsigned long long* __restrict__ LBg,
              unsigned int* __restrict__ C, float* __restrict__ LOSS,
              unsigned int* __restrict__ DONE, float* __restrict__ out)
{
  cg::grid_group grid = cg::this_grid();
  const int img = blockIdx.x / BPI;
  const int lb  = blockIdx.x - img*BPI;
  const int tid = threadIdx.x;
  const int lt  = lb*TPB + tid;
  const int lane = tid & 63;

  float* f    = Fg    + img*NPIX;
  float* life = LIFEg + img*NPIX;
  unsigned int* lbl = LBLg + img*NPIX;
  unsigned long long* me = MEg + img*NPIX;
  unsigned long long* lists[2] = { LAg + (size_t)img*NE, LBg + (size_t)img*NE };
  const float* pm = prob + img*NPIX;
  const float* rm = roi  + img*NPIX;

  __shared__ int   s_n;
  __shared__ float cand[TPB*5];
  __shared__ float s_val[TPB];
  __shared__ int   s_idx[TPB];

  // ---- fused init + round "-1": every pixel is a singleton root; fire
  // directly against its min incident edge (recompute neighbor f from inputs).
  for (int i = lt; i < NPIX; i += NT){
    int r = i >> 8, c = i & 255;
    float fi = 1.0f - pm[i]*rm[i];
    f[i] = fi;
    life[i] = 0.0f;
    me[i] = 0ULL;                         // any tagged value (round>=1) beats 0
    unsigned long long best = ~0ULL; int bj = 0; float bw = 0.0f; float bfj = 0.0f;
    if (c > 0){
      float fj = 1.0f - pm[i-1]*rm[i-1];
      float w = fmaxf(fj, fi);
      unsigned long long k = ((unsigned long long)__float_as_uint(w)<<17) | (unsigned)(r*255 + c - 1);
      if (k < best){ best = k; bj = i-1; bw = w; bfj = fj; }
    }
    if (c < 255){
      float fj = 1.0f - pm[i+1]*rm[i+1];
      float w = fmaxf(fj, fi);
      unsigned long long k = ((unsigned long long)__float_as_uint(w)<<17) | (unsigned)(r*255 + c);
      if (k < best){ best = k; bj = i+1; bw = w; bfj = fj; }
    }
    if (r > 0){
      float fj = 1.0f - pm[i-256]*rm[i-256];
      float w = fmaxf(fj, fi);
      unsigned long long k = ((unsigned long long)__float_as_uint(w)<<17) | (unsigned)(NRE + (r-1)*256 + c);
      if (k < best){ best = k; bj = i-256; bw = w; bfj = fj; }
    }
    if (r < 255){
      float fj = 1.0f - pm[i+256]*rm[i+256];
      float w = fmaxf(fj, fi);
      unsigned long long k = ((unsigned long long)__float_as_uint(w)<<17) | (unsigned)(NRE + r*256 + c);
      if (k < best){ best = k; bj = i+256; bw = w; bfj = fj; }
    }
    // opposite singleton root deeper (lex (f, idx)) -> this pixel dies now
    unsigned int l = (unsigned)i;
    if ((bfj < fi) || ((bfj == fi) && (bj < i))){ life[i] = bw - fi; l = (unsigned)bj; }
    lbl[i] = l;
  }
  {
    int gt = blockIdx.x*TPB + tid;
    if (gt < 2*NIMG + 1){ C[gt] = 0; }   // 8 list counters + DONE (DONE==&C[8])
  }
  grid.sync();

  // ---- rounds over compacted survivor lists ----
  int p = 0, n_prev = -1, roundIdx = 1, solo = 0;

  for (;;){
    unsigned long long tag = (unsigned long long)roundIdx << 48;
    unsigned long long* cur = lists[p];
    unsigned long long* src = lists[1-p];
    unsigned int* ctr = &C[p*NIMG + img];
    int M = (n_prev < 0) ? NE : n_prev;
    int Mpad = (M + 63) & ~63;

    if (solo){ if (tid == 0) s_n = 0; __syncthreads(); }
    const int my_lt = solo ? tid : lt;
    const int my_nt = solo ? TPB : NT;

    // phase 1: relabel -> compact survivors -> per-root min key (round-tagged atomicMax)
    for (int idx = my_lt; idx < Mpad; idx += my_nt){
      bool keep = false;
      int e = 0, a = 0, b = 0;
      if (idx < M){
        if (n_prev < 0){ e = idx; edge_uv(e, a, b); }
        else {
          unsigned long long ent = src[idx];
          e = (int)(ent & 0xFFFFFFFFu);
          a = (int)((ent >> 32) & 0xFFFF);
          b = (int)(ent >> 48);
        }
        a = find_root(lbl, a);
        b = find_root(lbl, b);
        keep = (a != b);
      }
      unsigned long long m = __ballot(keep);
      if (m){
        int pos = __popcll(m & ((1ULL<<lane) - 1));
        int leader = __ffsll((long long)m) - 1;
        int base = 0;
        if (lane == leader){
          int cnt = __popcll(m);
          base = solo ? atomicAdd(&s_n, cnt) : (int)atomicAdd(ctr, (unsigned)cnt);
        }
        base = __shfl(base, leader);
        if (keep){
          int u, v; edge_uv(e, u, v);
          float w = fmaxf(f[u], f[v]);
          unsigned long long kl = ((unsigned long long)__float_as_uint(w)<<17) | (unsigned)e;
          unsigned long long val = tag | (MASK48 - kl);   // w<=1.0 -> kl < 2^48
          atomicMax(&me[a], val);
          atomicMax(&me[b], val);
          cur[base + pos] = ((unsigned long long)(unsigned)b << 48) |
                            ((unsigned long long)(unsigned)a << 32) | (unsigned)e;
        }
      }
    }

    int n_new, total_active;
    if (solo){
      __syncthreads();
      n_new = s_n;
      total_active = n_new;
    } else {
      grid.sync();
      n_new = (int)C[p*NIMG + img];
      total_active = (int)C[p*NIMG+0] + (int)C[p*NIMG+1] + (int)C[p*NIMG+2] + (int)C[p*NIMG+3];
      if (total_active <= THRESH){
        if (lb != 0) return;            // non-leaders retire; no grid.sync beyond this point
        solo = 1;                       // from phase 2 onward this round
      } else if (lb == 0 && tid == 0){
        C[(1-p)*NIMG + img] = 0;        // ping-pong reset (ordered by phase-2 grid.sync)
      }
    }
    if (total_active == 0) break;       // nonempty list always produces >=1 fire

    // phase 2: fire — root dies via its min edge iff opposite round-start root deeper
    const int f2_lt = solo ? tid : lt;
    const int f2_nt = solo ? TPB : NT;
    for (int idx = f2_lt; idx < n_new; idx += f2_nt){
      unsigned long long ent = cur[idx];
      int e = (int)(ent & 0xFFFFFFFFu);
      int a = (int)((ent >> 32) & 0xFFFF);
      int b = (int)(ent >> 48);
      int u, v; edge_uv(e, u, v);
      float w = fmaxf(f[u], f[v]);
      unsigned long long kl = ((unsigned long long)__float_as_uint(w)<<17) | (unsigned)e;
      unsigned long long val = tag | (MASK48 - kl);
      float fa = f[a], fb = f[b];
      bool bd = (fb < fa) || ((fb == fa) && (b < a));
      int die  = bd ? a : b;
      int keepr= bd ? b : a;
      // atomic read: me was written by L2 atomics; plain load may hit stale L1 in solo mode
      unsigned long long cur_me = atomicMax(&me[die], 0ULL);
      if (cur_me == val){
        life[die] = w - (bd ? fa : fb);
        lbl[die] = (unsigned)keepr;
      }
    }
    if (solo) __syncthreads(); else grid.sync();

    p ^= 1; n_prev = n_new;
    if (++roundIdx >= MAXR) break;      // safety cap
  }

  // ---- top-5 lifetimes -> per-image loss (leader block only) ----
  float t5[5] = {-1.f,-1.f,-1.f,-1.f,-1.f};
  for (int i = tid; i < NPIX; i += TPB){
    float v = life[i];
    if (v > t5[4]){
      int j = 4;
      while (j > 0 && t5[j-1] < v){ t5[j] = t5[j-1]; --j; }
      t5[j] = v;
    }
  }
  #pragma unroll
  for (int k = 0; k < 5; ++k) cand[tid*5+k] = t5[k];
  __syncthreads();

  float lsum = 0.0f;
  for (int k = 0; k < 5; ++k){
    float bv = -1.0f; int bi = 0;
    #pragma unroll
    for (int j = 0; j < 5; ++j){
      float v = cand[tid*5+j];
      if (v > bv){ bv = v; bi = tid*5+j; }
    }
    s_val[tid] = bv; s_idx[tid] = bi;
    __syncthreads();
    for (int off = TPB>>1; off > 0; off >>= 1){
      if (tid < off && s_val[tid+off] > s_val[tid]){
        s_val[tid] = s_val[tid+off]; s_idx[tid] = s_idx[tid+off];
      }
      __syncthreads();
    }
    float win = s_val[0];
    if (tid == 0) cand[s_idx[0]] = -2.0f;   // exclude winner slot
    float d = win - 0.5f;                    // TARGET_LIFETIME
    lsum += d*d;
    __syncthreads();
  }

  // ---- fused finalize: last image leader writes the scalar output ----
  if (tid == 0){
    atomicExch(&LOSS[img], lsum * 0.2f);     // n_use = 5 always (65535 valid pairs)
    __threadfence();
    unsigned prev = atomicAdd(DONE, 1u);
    if (prev == NIMG - 1){
      float s = 0.0f;
      #pragma unroll
      for (int i = 0; i < NIMG; ++i) s += atomicAdd(&LOSS[i], 0.0f);  // L2 read
      out[0] = s * 25.0f;                    // mean over 4 * LOSS_SCALE(100)
    }
  }
}

extern "C" void kernel_launch(void* const* d_in, const int* in_sizes, int n_in,
                              void* d_out, int out_size, void* d_ws, size_t ws_size,
                              hipStream_t stream)
{
  const float* prob = (const float*)d_in[0];
  const float* roi  = (const float*)d_in[1];
  char* ws = (char*)d_ws;
  // layout: F 1MB | LIFE 1MB | LBL 1MB | ME 2MB | LA 4.18MB | LB 4.18MB | C+DONE | LOSS
  float*              F    = (float*)ws;
  float*              LIFE = (float*)(ws + (1<<20));
  unsigned int*       LBL  = (unsigned int*)(ws + (2<<20));
  unsigned long long* ME   = (unsigned long long*)(ws + (3<<20));
  unsigned long long* LA   = (unsigned long long*)(ws + (5<<20));
  unsigned long long* LB   = (unsigned long long*)(ws + (5<<20) + (size_t)4*NE*8);
  unsigned int*       C    = (unsigned int*)(ws + (5<<20) + (size_t)8*NE*8);
  unsigned int*       DONE = C + 2*NIMG;      // zeroed in-kernel with C
  float*              LOSS = (float*)(ws + (5<<20) + (size_t)8*NE*8 + 64);
  float*              out  = (float*)d_out;

  void* args[] = { (void*)&prob, (void*)&roi, (void*)&F, (void*)&LIFE, (void*)&LBL,
                   (void*)&ME, (void*)&LA, (void*)&LB, (void*)&C, (void*)&LOSS,
                   (void*)&DONE, (void*)&out };
  hipLaunchCooperativeKernel((void*)ph0_coop, dim3(NBLK), dim3(TPB), args, 0, stream);
}